// Round 11
// baseline (694.954 us; speedup 1.0000x reference)
//
#include <hip/hip_runtime.h>

#define BN_EPS 1e-5f

// ---------------- embedding: h = x @ W_emb + b_emb  (x is [N,4]) ----------------
__global__ void k_embed(const float* __restrict__ x, const float* __restrict__ Wemb,
                        const float* __restrict__ bemb, float* __restrict__ h, int N) {
    int t = blockIdx.x * blockDim.x + threadIdx.x;
    int n = t >> 6, c = t & 63;
    if (n >= N) return;
    const float* xr = x + (size_t)n * 4;
    float acc = bemb[c];
    acc += xr[0] * Wemb[0 * 64 + c];
    acc += xr[1] * Wemb[1 * 64 + c];
    acc += xr[2] * Wemb[2 * 64 + c];
    acc += xr[3] * Wemb[3 * 64 + c];
    h[t] = acc;
}

// ---------------- CSR build: histogram of dst ----------------
__global__ void k_hist(const int* __restrict__ dst, int* __restrict__ deg, int E) {
    int e = blockIdx.x * blockDim.x + threadIdx.x;
    if (e < E) atomicAdd(&deg[dst[e]], 1);
}

// ---------------- scan phase 1: per-block sums (1024 elems / 256-thread block) --
__global__ __launch_bounds__(256) void k_blocksum(const int* __restrict__ deg,
                                                  int* __restrict__ bsum, int N) {
    __shared__ int red[256];
    int tid = threadIdx.x;
    int base = blockIdx.x * 1024 + tid * 4;
    int s = 0;
    if (base + 3 < N) {
        int4 v = *(const int4*)&deg[base];
        s = v.x + v.y + v.z + v.w;
    } else {
        for (int i = 0; i < 4; ++i) if (base + i < N) s += deg[base + i];
    }
    red[tid] = s;
    __syncthreads();
    for (int d = 128; d > 0; d >>= 1) {
        if (tid < d) red[tid] += red[tid + d];
        __syncthreads();
    }
    if (tid == 0) bsum[blockIdx.x] = red[0];
}

// ---------------- scan phase 2: exclusive scan of block sums (nb <= 1024) -------
__global__ __launch_bounds__(1024) void k_scanpartials(int* __restrict__ bsum, int nb) {
    __shared__ int t[1024];
    int tid = threadIdx.x;
    int v = (tid < nb) ? bsum[tid] : 0;
    t[tid] = v;
    __syncthreads();
    for (int d = 1; d < 1024; d <<= 1) {
        int u = (tid >= d) ? t[tid - d] : 0;
        __syncthreads();
        t[tid] += u;
        __syncthreads();
    }
    if (tid < nb) bsum[tid] = t[tid] - v;  // exclusive
}

// ---------------- scan phase 3: per-block exclusive scan + offset, write rowptr -
__global__ __launch_bounds__(256) void k_applyscan(const int* __restrict__ deg,
                                                   const int* __restrict__ bsum,
                                                   int* __restrict__ rowptr, int N, int E) {
    __shared__ int red[256];
    int tid = threadIdx.x;
    int base = blockIdx.x * 1024 + tid * 4;
    int v0 = 0, v1 = 0, v2 = 0, v3 = 0;
    if (base + 3 < N) {
        int4 v = *(const int4*)&deg[base];
        v0 = v.x; v1 = v.y; v2 = v.z; v3 = v.w;
    } else {
        if (base < N) v0 = deg[base];
        if (base + 1 < N) v1 = deg[base + 1];
        if (base + 2 < N) v2 = deg[base + 2];
        if (base + 3 < N) v3 = deg[base + 3];
    }
    int s = v0 + v1 + v2 + v3;
    red[tid] = s;
    __syncthreads();
    for (int d = 1; d < 256; d <<= 1) {
        int u = (tid >= d) ? red[tid - d] : 0;
        __syncthreads();
        red[tid] += u;
        __syncthreads();
    }
    int off = bsum[blockIdx.x] + red[tid] - s;
    int r0 = off, r1 = off + v0, r2 = r1 + v1, r3 = r2 + v2;
    if (base < N)     rowptr[base] = r0;
    if (base + 1 < N) rowptr[base + 1] = r1;
    if (base + 2 < N) rowptr[base + 2] = r2;
    if (base + 3 < N) rowptr[base + 3] = r3;
    if (blockIdx.x == 0 && tid == 0) rowptr[N] = E;
}

// ---------------- init per-bucket cursors: gcur[b] = rowptr[b*256] --------------
__global__ void k_initbcur(const int* __restrict__ rowptr, int* __restrict__ gcur,
                           int NB, int N) {
    int b = blockIdx.x * blockDim.x + threadIdx.x;
    if (b < NB) {
        int node = b << 8; if (node > N) node = N;
        gcur[b] = rowptr[node];
    }
}

// ------- sort pass A: partition edges into 256-node buckets (requires N < 2^24) -
#define ABLK 8192
__global__ __launch_bounds__(1024) void k_binA(const int* __restrict__ src,
                                               const int* __restrict__ dst,
                                               const float* __restrict__ attr,
                                               int* __restrict__ gcur,
                                               unsigned long long* __restrict__ tmp,
                                               int E, int N) {
    __shared__ int hist[1024];
    __shared__ int lcur[1024];
    int tid = threadIdx.x;
    int NB = (N + 255) >> 8;  // <= 1024 for N <= 262144
    int e0 = blockIdx.x * ABLK;
    int e1 = e0 + ABLK; if (e1 > E) e1 = E;
    for (int i = tid; i < NB; i += 1024) hist[i] = 0;
    __syncthreads();
    for (int e = e0 + tid; e < e1; e += 1024) atomicAdd(&hist[dst[e] >> 8], 1);
    __syncthreads();
    for (int b = tid; b < NB; b += 1024) {
        int hc = hist[b];
        lcur[b] = hc ? atomicAdd(&gcur[b], hc) : 0;
    }
    __syncthreads();
    for (int e = e0 + tid; e < e1; e += 1024) {
        int d = dst[e];
        int pos = atomicAdd(&lcur[d >> 8], 1);
        unsigned long long p = ((unsigned long long)__float_as_uint(attr[e]) << 32) |
                               ((unsigned long long)(d & 255) << 24) |
                               (unsigned int)src[e];
        tmp[pos] = p;
    }
}

// ------- sort pass B: one block per bucket; exact node placement via LDS cursors.
__global__ __launch_bounds__(256) void k_binB(const int* __restrict__ rowptr,
                                              const unsigned long long* __restrict__ tmp,
                                              unsigned long long* __restrict__ edata,
                                              int N) {
    __shared__ int cur[256];
    int b = blockIdx.x;
    int tid = threadIdx.x;
    int nb0 = b << 8;
    int node = nb0 + tid;
    cur[tid] = (node < N) ? rowptr[node] : 0;
    int beg = rowptr[nb0];
    int endnode = nb0 + 256; if (endnode > N) endnode = N;
    int end = rowptr[endnode];
    __syncthreads();
    for (int e = beg + tid; e < end; e += 256) {
        unsigned long long p = tmp[e];
        int dl = (int)((p >> 24) & 255);
        int pos = atomicAdd(&cur[dl], 1);
        edata[pos] = p & 0xFFFFFFFF00FFFFFFull;  // clear dstlow: [attr | src]
    }
}

// ------- pull gather with lazy BN: S[n] = sum_e w_e * act(h_raw[src_e]) --------
__global__ void k_gather(const int* __restrict__ rowptr,
                         const unsigned long long* __restrict__ edata,
                         const float* __restrict__ h,
                         const float* __restrict__ scale, const float* __restrict__ shift,
                         int act,
                         float* __restrict__ S, float* __restrict__ degw, int N) {
    int t = blockIdx.x * blockDim.x + threadIdx.x;
    int n = t >> 6, c = t & 63;
    if (n >= N) return;
    float sc = 1.f, sh = 0.f;
    if (act) { sc = scale[c]; sh = shift[c]; }
    int beg = rowptr[n], end = rowptr[n + 1];
    int len = end - beg;
    float acc[8] = {0.f, 0.f, 0.f, 0.f, 0.f, 0.f, 0.f, 0.f};
    float wsum = 0.f;
    for (int base = 0; base < len; base += 8) {
#pragma unroll
        for (int i = 0; i < 8; ++i) {
            int idx = base + i;
            int ce = beg + (idx < len ? idx : len - 1);  // wave-uniform predicate
            unsigned long long p = edata[ce];
            float w = (idx < len) ? __uint_as_float((unsigned int)(p >> 32)) : 0.f;
            int s = (int)(unsigned int)p;
            float v = h[(size_t)s * 64 + c];
            if (act) v = fmaxf(fmaf(v, sc, sh), 0.f);
            acc[i] += w * v;
            wsum += w;
        }
    }
    float r = ((acc[0] + acc[1]) + (acc[2] + acc[3])) +
              ((acc[4] + acc[5]) + (acc[6] + acc[7]));
    S[(size_t)n * 64 + c] = r;
    if (c == 0) degw[n] = wsum;
}

// --- h_raw_out = S@W1 + x@W3 - dw*(x@W2) + dw*b1 + b3 (in place, x=act(h_raw));
// Register-resident row data + readlane broadcast: lane = channel, each wave
// holds 8 rows of S and act(h) in VGPRs; S[r][k] / x[r][k] extracted with
// v_readlane (wave-uniform k -> SGPR, legal FMA scalar operand). Zero LDS
// traffic in the inner loop except 3 conflict-free weight reads per k,
// amortized over 24 FMAs. Old version was LDS-issue-bound (11 reads / 12 FMA).
__global__ __launch_bounds__(256, 4) void k_update(
    const float* __restrict__ S, float* __restrict__ h,
    const float* __restrict__ degw,
    const float* __restrict__ scale, const float* __restrict__ shift, int act,
    const float* __restrict__ W1, const float* __restrict__ b1,
    const float* __restrict__ W2, const float* __restrict__ W3,
    const float* __restrict__ b3,
    float* __restrict__ bnstats, int N) {
    __shared__ float W1s[4096], W2s[4096], W3s[4096];
    __shared__ float red[512];
    int tid = threadIdx.x;
    for (int i = tid * 4; i < 4096; i += 1024) {
        *(float4*)&W1s[i] = *(const float4*)&W1[i];
        *(float4*)&W2s[i] = *(const float4*)&W2[i];
        *(float4*)&W3s[i] = *(const float4*)&W3[i];
    }
    int c = tid & 63;   // lane = channel
    int wv = tid >> 6;  // wave 0..3; block covers 32 rows per chunk (4 waves x 8)
    float sc = 1.f, sh = 0.f;
    if (act) { sc = scale[c]; sh = shift[c]; }
    float b1c = b1[c], b3c = b3[c];
    float bsum = 0.f, bsq = 0.f;
    __syncthreads();

    int numChunks = (N + 31) / 32;
    for (int chunk = blockIdx.x; chunk < numChunks; chunk += gridDim.x) {
        int r0 = chunk * 32 + wv * 8;
        float sreg[8], xreg[8], dwreg[8];
#pragma unroll
        for (int r = 0; r < 8; ++r) {
            int row = r0 + r;
            if (row < N) {
                sreg[r] = S[(size_t)row * 64 + c];
                float v = h[(size_t)row * 64 + c];
                if (act) v = fmaxf(fmaf(v, sc, sh), 0.f);
                xreg[r] = v;
                dwreg[r] = degw[row];
            } else {
                sreg[r] = 0.f; xreg[r] = 0.f; dwreg[r] = 0.f;
            }
        }
        float accA[8], accB[8], accC[8];
#pragma unroll
        for (int r = 0; r < 8; ++r) { accA[r] = 0.f; accB[r] = 0.f; accC[r] = 0.f; }
#pragma unroll 8
        for (int k = 0; k < 64; ++k) {
            float w1 = W1s[k * 64 + c];
            float w2 = W2s[k * 64 + c];
            float w3 = W3s[k * 64 + c];
#pragma unroll
            for (int r = 0; r < 8; ++r) {
                float sv = __int_as_float(
                    __builtin_amdgcn_readlane(__float_as_int(sreg[r]), k));
                float xv = __int_as_float(
                    __builtin_amdgcn_readlane(__float_as_int(xreg[r]), k));
                accA[r] = fmaf(sv, w1, accA[r]);
                accB[r] = fmaf(xv, w2, accB[r]);
                accC[r] = fmaf(xv, w3, accC[r]);
            }
        }
#pragma unroll
        for (int r = 0; r < 8; ++r) {
            int row = r0 + r;
            if (row < N) {
                float dw = dwreg[r];
                float val = accA[r] + accC[r] - dw * accB[r] + dw * b1c + b3c;
                h[(size_t)row * 64 + c] = val;  // raw (pre-BN); rows already in regs
                bsum += val;
                bsq += val * val;
            }
        }
    }

    // ---- BN stats reduction ----
    __syncthreads();
    red[tid] = bsum;
    red[256 + tid] = bsq;
    __syncthreads();
    if (tid < 64) {
        float s = red[tid] + red[tid + 64] + red[tid + 128] + red[tid + 192];
        float q = red[256 + tid] + red[256 + tid + 64] + red[256 + tid + 128] + red[256 + tid + 192];
        atomicAdd(&bnstats[tid], s);
        atomicAdd(&bnstats[64 + tid], q);
    }
}

// ---------------- finalize BN: scale/shift per channel ----------------
__global__ void k_bnfinish(const float* __restrict__ bnstats,
                           const float* __restrict__ gamma, const float* __restrict__ beta,
                           float* __restrict__ scale, float* __restrict__ shift, int N) {
    int c = threadIdx.x;
    float inv_n = 1.0f / (float)N;
    float mean = bnstats[c] * inv_n;
    float var = bnstats[64 + c] * inv_n - mean * mean;
    float sc = gamma[c] * rsqrtf(fmaxf(var, 0.f) + BN_EPS);
    scale[c] = sc;
    shift[c] = beta[c] - mean * sc;
}

// ------- pool phase 1: per-graph sums of act(h_raw), sorted-run + atomics -------
#define POOL_TILE 128
__global__ __launch_bounds__(256) void k_poolsum(const float* __restrict__ h,
                                                 const int* __restrict__ batch,
                                                 const float* __restrict__ scale,
                                                 const float* __restrict__ shift,
                                                 float* __restrict__ gsums, int N) {
    int tid = threadIdx.x;
    int c = tid & 63, q = tid >> 6;
    float sc = scale[c], sh_ = shift[c];
    int n0 = blockIdx.x * POOL_TILE;
    int nEnd = n0 + POOL_TILE; if (nEnd > N) nEnd = N;
    int g = -1;
    float acc = 0.f;
    for (int n = n0 + q; n < nEnd; n += 4) {
        int b = batch[n];
        if (b != g) {
            if (g >= 0) atomicAdd(&gsums[(size_t)g * 64 + c], acc);
            g = b; acc = 0.f;
        }
        acc += fmaxf(fmaf(h[(size_t)n * 64 + c], sc, sh_), 0.f);
    }
    if (g >= 0) atomicAdd(&gsums[(size_t)g * 64 + c], acc);
}

// ------- pool phase 2: divide by count + MLP head (one 64-thread block / graph) -
__global__ void k_head(const float* __restrict__ gsums, const int* __restrict__ batch,
                       const float* __restrict__ Wl1, const float* __restrict__ bl1,
                       const float* __restrict__ Wl2, const float* __restrict__ bl2,
                       float* __restrict__ out, int N) {
    int g = blockIdx.x;
    int c = threadIdx.x;  // 64 threads
    int lo = 0, hi = N;
    while (lo < hi) { int mid = (lo + hi) >> 1; if (batch[mid] < g) lo = mid + 1; else hi = mid; }
    int start = lo;
    hi = N;
    while (lo < hi) { int mid = (lo + hi) >> 1; if (batch[mid] < g + 1) lo = mid + 1; else hi = mid; }
    int cnt = lo - start;
    float denom = (float)(cnt > 0 ? cnt : 1);
    __shared__ float gS[64], yS[64];
    gS[c] = gsums[(size_t)g * 64 + c] / denom;
    __syncthreads();
    float y = bl1[c];
    for (int k = 0; k < 64; ++k) y += gS[k] * Wl1[k * 64 + c];
    yS[c] = fmaxf(y, 0.f);
    __syncthreads();
    if (c < 3) {
        float o = bl2[c];
        for (int k = 0; k < 64; ++k) o += yS[k] * Wl2[k * 3 + c];
        out[g * 3 + c] = o;
    }
}

extern "C" void kernel_launch(void* const* d_in, const int* in_sizes, int n_in,
                              void* d_out, int out_size, void* d_ws, size_t ws_size,
                              hipStream_t stream) {
    const float* x     = (const float*)d_in[0];
    const int*   eid   = (const int*)d_in[1];
    const float* attr  = (const float*)d_in[2];
    const int*   batch = (const int*)d_in[3];
    const float* Wemb  = (const float*)d_in[4];
    const float* bemb  = (const float*)d_in[5];
    const float* W1    = (const float*)d_in[6];
    const float* b1    = (const float*)d_in[7];
    const float* W2    = (const float*)d_in[8];
    const float* W3    = (const float*)d_in[9];
    const float* b3    = (const float*)d_in[10];
    const float* gamma = (const float*)d_in[11];
    const float* beta  = (const float*)d_in[12];
    const float* Wl1   = (const float*)d_in[13];
    const float* bl1   = (const float*)d_in[14];
    const float* Wl2   = (const float*)d_in[15];
    const float* bl2   = (const float*)d_in[16];

    int N = in_sizes[3];
    int E = in_sizes[2];
    int L = in_sizes[7] / 64;
    int G = out_size / 3;

    const int* src = eid;
    const int* dst = eid + E;

    float* ws      = (float*)d_ws;
    float* h       = ws;                       // N*64
    float* S       = h + (size_t)N * 64;       // N*64
    float* degw    = S + (size_t)N * 64;       // N
    float* bnstats = degw + N;                 // 128
    float* bnscale = bnstats + 128;            // 64
    float* bnshift = bnscale + 64;             // 64
    float* gsums   = bnshift + 64;             // G*64
    int*   deg     = (int*)(gsums + (size_t)G * 64);  // N
    int*   rowptr  = deg + N;                  // N+2
    int*   bsum    = rowptr + (N + 2);         // 1024
    int*   gcur    = bsum + 1024;              // 1024 (bucket cursors)
    unsigned long long* edata = (unsigned long long*)(gcur + 1024);  // E
    unsigned long long* tmp   = edata + E;                           // E

    int nScanBlocks = (N + 1023) / 1024;
    int NB = (N + 255) >> 8;  // 256-node buckets (requires N < 2^24, NB <= 1024)

    // ---- CSR build + two-level counting sort of edges by dst ----
    hipMemsetAsync(deg, 0, (size_t)N * sizeof(int), stream);
    k_embed<<<(N * 64 + 255) / 256, 256, 0, stream>>>(x, Wemb, bemb, h, N);
    k_hist<<<(E + 255) / 256, 256, 0, stream>>>(dst, deg, E);
    k_blocksum<<<nScanBlocks, 256, 0, stream>>>(deg, bsum, N);
    k_scanpartials<<<1, 1024, 0, stream>>>(bsum, nScanBlocks);
    k_applyscan<<<nScanBlocks, 256, 0, stream>>>(deg, bsum, rowptr, N, E);
    k_initbcur<<<(NB + 255) / 256, 256, 0, stream>>>(rowptr, gcur, NB, N);
    k_binA<<<(E + ABLK - 1) / ABLK, 1024, 0, stream>>>(src, dst, attr, gcur, tmp, E, N);
    k_binB<<<NB, 256, 0, stream>>>(rowptr, tmp, edata, N);

    // ---- layers: split kernels (high occupancy), lazy BN (no bnapply pass) ----
    int updGrid = 3 * 256;  // 3 blocks/CU (LDS-limited) x 256 CUs
    for (int l = 0; l < L; ++l) {
        int act = (l > 0) ? 1 : 0;
        hipMemsetAsync(bnstats, 0, 128 * sizeof(float), stream);
        k_gather<<<(N * 64 + 255) / 256, 256, 0, stream>>>(
            rowptr, edata, h, bnscale, bnshift, act, S, degw, N);
        k_update<<<updGrid, 256, 0, stream>>>(S, h, degw, bnscale, bnshift, act,
                                              W1 + (size_t)l * 4096, b1 + (size_t)l * 64,
                                              W2 + (size_t)l * 4096, W3 + (size_t)l * 4096,
                                              b3 + (size_t)l * 64, bnstats, N);
        k_bnfinish<<<1, 64, 0, stream>>>(bnstats, gamma + (size_t)l * 64,
                                         beta + (size_t)l * 64, bnscale, bnshift, N);
    }

    // ---- pool (applies final BN affine + relu lazily) + head ----
    hipMemsetAsync(gsums, 0, (size_t)G * 64 * sizeof(float), stream);
    k_poolsum<<<(N + POOL_TILE - 1) / POOL_TILE, 256, 0, stream>>>(
        h, batch, bnscale, bnshift, gsums, N);
    k_head<<<G, 64, 0, stream>>>(gsums, batch, Wl1, bl1, Wl2, bl2, (float*)d_out, N);
}